// Round 2
// baseline (135.527 us; speedup 1.0000x reference)
//
#include <hip/hip_runtime.h>
#include <stdint.h>

#define SEQ   4096
#define DIN   1024

typedef __attribute__((ext_vector_type(8))) short bf16x8;
typedef __attribute__((ext_vector_type(4))) float floatx4;
typedef __attribute__((ext_vector_type(4))) unsigned short ushortx4;

#if __has_builtin(__builtin_amdgcn_exp2f)
#define EXP2(x) __builtin_amdgcn_exp2f(x)
#else
#define EXP2(x) exp2f(x)
#endif

__device__ __forceinline__ unsigned short f2bf(float f) {
    union { float f; unsigned int u; } v; v.f = f;
    unsigned int u = v.u + 0x7fffu + ((v.u >> 16) & 1u);
    return (unsigned short)(u >> 16);
}
__device__ __forceinline__ float bf2f(unsigned short h) {
    union { unsigned int u; float f; } v; v.u = ((unsigned int)h) << 16;
    return v.f;
}
__device__ __forceinline__ float uasf(unsigned int u) {
    union { unsigned int u; float f; } v; v.u = u; return v.f;
}
__device__ __forceinline__ unsigned int fasu(float f) {
    union { float f; unsigned int u; } v; v.f = f; return v.u;
}

// ---------------- prep: WT[mat*64+n][k] = bf16(W[k][n]) ----------------
// Coalesced both sides via 64x64 LDS transpose tile (old version did
// 256B-strided scalar reads). 48 blocks = 3 mats x 16 k-tiles.
__global__ void wt_prep(const float* __restrict__ Wq, const float* __restrict__ Wk,
                        const float* __restrict__ Wv, unsigned short* __restrict__ WT) {
    __shared__ float Tt[64][65];
    const int tid = threadIdx.x;
    const int mat = blockIdx.x >> 4, kt = blockIdx.x & 15, k0 = kt * 64;
    const float* W = (mat == 0) ? Wq : ((mat == 1) ? Wk : Wv);
#pragma unroll
    for (int i = 0; i < 4; i++) {
        int u = i * 256 + tid, r = u >> 4, c = u & 15;
        floatx4 ld = *(const floatx4*)(W + (size_t)(k0 + r) * 64 + c * 4);
#pragma unroll
        for (int j = 0; j < 4; j++) Tt[r][c * 4 + j] = ld[j];
    }
    __syncthreads();
#pragma unroll
    for (int i = 0; i < 2; i++) {
        int v = i * 256 + tid, n = v >> 3, k8 = v & 7;
        bf16x8 w;
#pragma unroll
        for (int j = 0; j < 8; j++) w[j] = (short)f2bf(Tt[k8 * 8 + j][n]);
        *(bf16x8*)&WT[(size_t)(mat * 64 + n) * 1024 + k0 + k8 * 8] = w;
    }
}

// ---------------- projection: q,k,v = x @ W{q,k,v} ----------------
// grid 256, block 512 (8 waves = 4 row-strips x 2 col-groups). BM=64:
// W re-stage traffic 96 MB + X 64 MB; ~11 TB/s per-CU-return ceiling
// => ~15 us floor. Double-buffered reg-prefetch, one barrier per chunk.
#define QSCALE 0.18033688011112042f
__launch_bounds__(512, 2)
__global__ void proj_qkv(const float* __restrict__ X, const unsigned short* __restrict__ WT,
                         unsigned short* __restrict__ qb, unsigned short* __restrict__ kb,
                         unsigned short* __restrict__ vb) {
    __shared__ __align__(16) float          X0[64 * 64], X1[64 * 64];     // 16 KB each
    __shared__ __align__(16) unsigned short W0[192 * 64], W1[192 * 64];   // 24 KB each
    const int tid = threadIdx.x;
    const int wave = tid >> 6, lane = tid & 63;
    const int quad = lane >> 4, l16 = lane & 15;
    const int strip = wave >> 1;            // rows strip*16..+16
    const int cg = wave & 1;                // cols cg*96..+96
    const int row0 = blockIdx.x * 64;
    const int m = strip * 16 + l16;

    floatx4 acc[6];
#pragma unroll
    for (int i = 0; i < 6; i++) acc[i] = (floatx4){0.f, 0.f, 0.f, 0.f};

    int xu[2], xr[2], xc[2], wu[3], wr[3], wc[3];
#pragma unroll
    for (int i = 0; i < 2; i++) {
        xu[i] = i * 512 + tid; xr[i] = xu[i] >> 4; xc[i] = (xu[i] & 15) ^ (xr[i] & 15);
    }
#pragma unroll
    for (int i = 0; i < 3; i++) {
        wu[i] = i * 512 + tid; wr[i] = wu[i] >> 3; wc[i] = (wu[i] & 7) ^ (wr[i] & 7);
    }
    floatx4 xpre[2], wpre[3];
    auto issue = [&](int k0) {
#pragma unroll
        for (int i = 0; i < 2; i++)
            xpre[i] = *(const floatx4*)(X + (size_t)(row0 + xr[i]) * DIN + k0 + xc[i] * 4);
#pragma unroll
        for (int i = 0; i < 3; i++)
            wpre[i] = *(const floatx4*)(WT + (size_t)wr[i] * 1024 + k0 + wc[i] * 8);
    };

    issue(0);
    for (int kc = 0; kc < 16; kc++) {
        float*          Xd = (kc & 1) ? X1 : X0;
        unsigned short* Wd = (kc & 1) ? W1 : W0;
#pragma unroll
        for (int i = 0; i < 2; i++) *(floatx4*)&Xd[xu[i] * 4] = xpre[i];
#pragma unroll
        for (int i = 0; i < 3; i++) *(floatx4*)&Wd[wu[i] * 8] = wpre[i];
        if (kc < 15) issue((kc + 1) * 64);   // in flight across the barrier
        __syncthreads();

        bf16x8 af[2];
#pragma unroll
        for (int ks = 0; ks < 2; ks++) {
            floatx4 x0 = *(const floatx4*)&Xd[m * 64 + ((ks * 8 + quad * 2 + 0) ^ (m & 15)) * 4];
            floatx4 x1 = *(const floatx4*)&Xd[m * 64 + ((ks * 8 + quad * 2 + 1) ^ (m & 15)) * 4];
#pragma unroll
            for (int j = 0; j < 4; j++) {
                af[ks][j]     = (short)f2bf(x0[j]);
                af[ks][j + 4] = (short)f2bf(x1[j]);
            }
        }
#pragma unroll
        for (int i = 0; i < 6; i++) {
            const int nrow = (cg * 6 + i) * 16 + l16;
#pragma unroll
            for (int ks = 0; ks < 2; ks++) {
                const int c = ks * 4 + quad;
                bf16x8 bfrag = *(const bf16x8*)&Wd[nrow * 64 + (c ^ (nrow & 7)) * 8];
                acc[i] = __builtin_amdgcn_mfma_f32_16x16x32_bf16(af[ks], bfrag, acc[i], 0, 0, 0);
            }
        }
    }
#pragma unroll
    for (int i = 0; i < 6; i++) {
        const int nt = cg * 6 + i;
        const int mat = nt >> 2;
        const int col = (nt & 3) * 16 + l16;
#pragma unroll
        for (int r = 0; r < 4; r++) {
            const int orow = row0 + strip * 16 + quad * 4 + r;
            float v = acc[i][r];
            if (mat == 0) {
                qb[(size_t)orow * 64 + col] = f2bf(v * QSCALE);
            } else if (mat == 1) {
                kb[(size_t)orow * 64 + col] = f2bf(v);
            } else {  // v stored transposed: vb[b][d][s]
                int b = orow >> 12, sq = orow & 4095;
                vb[((size_t)b * 64 + col) * SEQ + sq] = f2bf(v);
            }
        }
    }
}

// ---------------- flash attention, causal, fixed-base softmax ----------------
// Q-tile 128 (4 waves x 32 q-rows = 2 strips each): every K/V fragment read
// from LDS feeds 2 MFMAs -> LDS clk per unit work drops ~1.7x (the measured
// bottleneck pipe; softmax VALU was proven non-critical in R0/R1).
// K/V double-buffered, ONE barrier per 64-key tile (write next tile + issue
// prefetch BEFORE the barrier, compute after). Split-K 8 -> grid
// 32 qt x 4 batch x 8 = 1024 blocks; 50 KB LDS -> 3 blocks/CU resident.
// Empty splits write zeros so merge is unconditional.
__launch_bounds__(256, 3)
__global__ void attn(const unsigned short* __restrict__ qb, const unsigned short* __restrict__ kb,
                     const unsigned short* __restrict__ vb, unsigned short* __restrict__ opart,
                     float* __restrict__ lpart) {
    __shared__ __align__(16) unsigned short K0[64 * 64], K1[64 * 64];   // 8 KB each [key][d] swz
    __shared__ __align__(16) unsigned short V0[64 * 64], V1[64 * 64];   // 8 KB each [d][key] swz
    __shared__ __align__(16) unsigned short Pl[4][32 * 72];             // 18 KB [q32][key64+pad]

    const int bid = blockIdx.x;
    const int qt = 31 - (bid >> 5);          // heavy (large qt) dispatched first
    const int batch = (bid >> 3) & 3;
    const int s = bid & 7;
    const int q0 = qt * 128;
    const int T = 2 * qt + 2;                // 64-key tiles in causal range
    const int lo = (T * s) >> 3, hi = (T * (s + 1)) >> 3;

    const int tid = threadIdx.x;
    const int wave = tid >> 6, lane = tid & 63;
    const int quad = lane >> 4, l16 = lane & 15;

    const unsigned short* qr = qb + (size_t)(batch * SEQ + q0 + wave * 32 + l16) * 64;
    bf16x8 qa[2][2];                         // [strip][ks]
    qa[0][0] = *(const bf16x8*)(qr + quad * 8);
    qa[0][1] = *(const bf16x8*)(qr + 32 + quad * 8);
    qa[1][0] = *(const bf16x8*)(qr + 16 * 64 + quad * 8);
    qa[1][1] = *(const bf16x8*)(qr + 16 * 64 + 32 + quad * 8);

    floatx4 o[2][4];                         // o[st][nt][r] = O[q=l16 of strip][d=nt*16+quad*4+r]
#pragma unroll
    for (int st = 0; st < 2; st++)
#pragma unroll
        for (int i = 0; i < 4; i++) o[st][i] = (floatx4){0.f, 0.f, 0.f, 0.f};
    float ls[2] = {0.f, 0.f};

    const unsigned short* kbase = kb + (size_t)batch * SEQ * 64;
    const unsigned short* vbase = vb + (size_t)batch * 64 * SEQ;
    unsigned short* P = &Pl[wave][0];

    // staging: K 512 16B-units + V 512 units, 2+2 per thread
    int ku[2], kr[2], kc_[2], vu[2], vd[2], vc[2];
#pragma unroll
    for (int i = 0; i < 2; i++) {
        ku[i] = i * 256 + tid; kr[i] = ku[i] >> 3; kc_[i] = (ku[i] & 7) ^ (kr[i] & 7);
        vu[i] = i * 256 + tid; vd[i] = vu[i] >> 3; vc[i] = (vu[i] & 7) ^ (vd[i] & 7);
    }
    floatx4 kpre[2], vpre[2];
    auto issue = [&](int k0) {
#pragma unroll
        for (int i = 0; i < 2; i++)
            kpre[i] = *(const floatx4*)(kbase + (size_t)(k0 + kr[i]) * 64 + kc_[i] * 8);
#pragma unroll
        for (int i = 0; i < 2; i++)
            vpre[i] = *(const floatx4*)(vbase + (size_t)vd[i] * SEQ + k0 + vc[i] * 8);
    };

    if (lo < hi) issue(lo * 64);
    for (int kt = lo; kt < hi; kt++) {
        unsigned short* Kd = (kt & 1) ? K1 : K0;
        unsigned short* Vd = (kt & 1) ? V1 : V0;
        // write tile kt into its buffer (other buffer still being read is kt-1's;
        // buf[kt&1] readers finished before the PREVIOUS barrier)
#pragma unroll
        for (int i = 0; i < 2; i++) *(floatx4*)&Kd[ku[i] * 8] = kpre[i];
#pragma unroll
        for (int i = 0; i < 2; i++) *(floatx4*)&Vd[vu[i] * 8] = vpre[i];
        if (kt + 1 < hi) issue((kt + 1) * 64);   // lands during compute below
        __syncthreads();                     // publishes tile kt

        const int k0 = kt * 64;
        // S^T: sc[st][nt][r] = S[q=l16 of strip][key=k0+nt*16+quad*4+r]
        floatx4 sc[2][4];
#pragma unroll
        for (int st = 0; st < 2; st++)
#pragma unroll
            for (int nt = 0; nt < 4; nt++) sc[st][nt] = (floatx4){0.f, 0.f, 0.f, 0.f};
#pragma unroll
        for (int ks = 0; ks < 2; ks++) {
#pragma unroll
            for (int nt = 0; nt < 4; nt++) {
                const int key = nt * 16 + l16;
                bf16x8 ak = *(const bf16x8*)&Kd[key * 64 + (((ks * 4 + quad)) ^ (key & 7)) * 8];
                sc[0][nt] = __builtin_amdgcn_mfma_f32_16x16x32_bf16(ak, qa[0][ks], sc[0][nt], 0, 0, 0);
                sc[1][nt] = __builtin_amdgcn_mfma_f32_16x16x32_bf16(ak, qa[1][ks], sc[1][nt], 0, 0, 0);
            }
        }
        if (kt >= T - 2) {                   // diagonal region: causal mask
#pragma unroll
            for (int st = 0; st < 2; st++) {
                const int qg = q0 + wave * 32 + st * 16 + l16;
#pragma unroll
                for (int nt = 0; nt < 4; nt++)
#pragma unroll
                    for (int r = 0; r < 4; r++) {
                        const int kg = k0 + nt * 16 + quad * 4 + r;
                        if (kg > qg) sc[st][nt][r] = -1e30f;
                    }
            }
        }
#pragma unroll
        for (int st = 0; st < 2; st++) {
#pragma unroll
            for (int nt = 0; nt < 4; nt++) {
                // p = exp2(s) (fixed-base softmax, log2 domain, q pre-scaled)
                float v0 = EXP2(sc[st][nt][0]), v1 = EXP2(sc[st][nt][1]);
                float v2 = EXP2(sc[st][nt][2]), v3 = EXP2(sc[st][nt][3]);
                // truncate to bf16; lsum accumulates the SAME truncated values
                unsigned int u0 = fasu(v0) & 0xffff0000u, u1 = fasu(v1) & 0xffff0000u;
                unsigned int u2 = fasu(v2) & 0xffff0000u, u3 = fasu(v3) & 0xffff0000u;
                ls[st] += (uasf(u0) + uasf(u1)) + (uasf(u2) + uasf(u3));
                uint2 w;
                w.x = (u0 >> 16) | u1;       // keys quad*4+0, +1
                w.y = (u2 >> 16) | u3;       // keys quad*4+2, +3
                *(uint2*)&P[(st * 16 + l16) * 72 + nt * 16 + quad * 4] = w;
            }
        }
        // PV: O^T = A=V^T (vb is [d][s]) x B=P^T; V frag shared by both strips
#pragma unroll
        for (int ks = 0; ks < 2; ks++) {
            bf16x8 pb0 = *(const bf16x8*)&P[(0  + l16) * 72 + ks * 32 + quad * 8];
            bf16x8 pb1 = *(const bf16x8*)&P[(16 + l16) * 72 + ks * 32 + quad * 8];
#pragma unroll
            for (int nt = 0; nt < 4; nt++) {
                const int d = nt * 16 + l16;
                bf16x8 av = *(const bf16x8*)&Vd[d * 64 + (((ks * 4 + quad)) ^ (d & 7)) * 8];
                o[0][nt] = __builtin_amdgcn_mfma_f32_16x16x32_bf16(av, pb0, o[0][nt], 0, 0, 0);
                o[1][nt] = __builtin_amdgcn_mfma_f32_16x16x32_bf16(av, pb1, o[1][nt], 0, 0, 0);
            }
        }
    }

    // epilogue: un-normalized bf16 partial + row sums (zeros if empty split)
    unsigned short* ob = opart + (size_t)s * (4 * SEQ * 64)
                       + (size_t)(batch * SEQ + q0 + wave * 32) * 64;
    float* lb = lpart + (size_t)s * (4 * SEQ) + (batch * SEQ + q0 + wave * 32);
#pragma unroll
    for (int st = 0; st < 2; st++) {
        float l = ls[st];
        l += __shfl_xor(l, 16);
        l += __shfl_xor(l, 32);
#pragma unroll
        for (int nt = 0; nt < 4; nt++) {     // lane holds 4 contiguous d's: 8B store
            ushortx4 w;
#pragma unroll
            for (int r = 0; r < 4; r++) w[r] = f2bf(o[st][nt][r]);
            *(ushortx4*)&ob[(st * 16 + l16) * 64 + nt * 16 + quad * 4] = w;
        }
        if (quad == 0) lb[st * 16 + l16] = l;
    }
}

// ---------------- merge the eight split-K partials ----------------
__global__ void merge(const unsigned short* __restrict__ opart, const float* __restrict__ lpart,
                      float* __restrict__ out) {
    int idx = blockIdx.x * 256 + threadIdx.x;   // [0, 262144): 4-col units
    int row = idx >> 4, c4 = idx & 15;
    float l = 0.f;
#pragma unroll
    for (int s = 0; s < 8; s++) l += lpart[s * 4 * SEQ + row];
    float inv = 1.f / l;
    floatx4 acc = (floatx4){0.f, 0.f, 0.f, 0.f};
#pragma unroll
    for (int s = 0; s < 8; s++) {
        ushortx4 u = *(const ushortx4*)(opart + (size_t)s * (4 * SEQ * 64)
                                        + (size_t)row * 64 + c4 * 4);
#pragma unroll
        for (int j = 0; j < 4; j++) acc[j] += bf2f(u[j]);
    }
    acc *= inv;
    *(floatx4*)(out + (size_t)row * 64 + c4 * 4) = acc;
}

extern "C" void kernel_launch(void* const* d_in, const int* in_sizes, int n_in,
                              void* d_out, int out_size, void* d_ws, size_t ws_size,
                              hipStream_t stream) {
    const float* X  = (const float*)d_in[0];
    const float* Wq = (const float*)d_in[1];
    const float* Wk = (const float*)d_in[2];
    const float* Wv = (const float*)d_in[3];
    float* out = (float*)d_out;
    char* ws = (char*)d_ws;
    unsigned short* WT    = (unsigned short*)(ws + 0);          // 384 KB
    unsigned short* qb    = (unsigned short*)(ws + 393216);     // 2 MB
    unsigned short* kb    = (unsigned short*)(ws + 2490368);    // 2 MB
    unsigned short* vb    = (unsigned short*)(ws + 4587520);    // 2 MB
    unsigned short* opart = (unsigned short*)(ws + 6684672);    // 16 MB (8 slots, bf16)
    float*          lpart = (float*)(ws + 23461888);            // 512 KB

    hipLaunchKernelGGL(wt_prep,  dim3(48),   dim3(256), 0, stream, Wq, Wk, Wv, WT);
    hipLaunchKernelGGL(proj_qkv, dim3(256),  dim3(512), 0, stream, X, WT, qb, kb, vb);
    hipLaunchKernelGGL(attn,     dim3(1024), dim3(256), 0, stream, qb, kb, vb, opart, lpart);
    hipLaunchKernelGGL(merge,    dim3(1024), dim3(256), 0, stream, opart, lpart, out);
}

// Round 3
// 132.945 us; speedup vs baseline: 1.0194x; 1.0194x over previous
//
#include <hip/hip_runtime.h>
#include <stdint.h>

#define SEQ   4096
#define DIN   1024

typedef __attribute__((ext_vector_type(8))) short bf16x8;
typedef __attribute__((ext_vector_type(4))) float floatx4;
typedef __attribute__((ext_vector_type(4))) unsigned short ushortx4;

#if __has_builtin(__builtin_amdgcn_exp2f)
#define EXP2(x) __builtin_amdgcn_exp2f(x)
#else
#define EXP2(x) exp2f(x)
#endif

__device__ __forceinline__ unsigned short f2bf(float f) {
    union { float f; unsigned int u; } v; v.f = f;
    unsigned int u = v.u + 0x7fffu + ((v.u >> 16) & 1u);
    return (unsigned short)(u >> 16);
}
__device__ __forceinline__ float bf2f(unsigned short h) {
    union { unsigned int u; float f; } v; v.u = ((unsigned int)h) << 16;
    return v.f;
}
__device__ __forceinline__ float uasf(unsigned int u) {
    union { unsigned int u; float f; } v; v.u = u; return v.f;
}
__device__ __forceinline__ unsigned int fasu(float f) {
    union { float f; unsigned int u; } v; v.f = f; return v.u;
}

// ---------------- prep: WT[mat*64+n][k] = bf16(W[k][n]) ----------------
// Coalesced both sides via 64x64 LDS transpose tile. 48 blocks = 3 mats x 16 k-tiles.
__global__ void wt_prep(const float* __restrict__ Wq, const float* __restrict__ Wk,
                        const float* __restrict__ Wv, unsigned short* __restrict__ WT) {
    __shared__ float Tt[64][65];
    const int tid = threadIdx.x;
    const int mat = blockIdx.x >> 4, kt = blockIdx.x & 15, k0 = kt * 64;
    const float* W = (mat == 0) ? Wq : ((mat == 1) ? Wk : Wv);
#pragma unroll
    for (int i = 0; i < 4; i++) {
        int u = i * 256 + tid, r = u >> 4, c = u & 15;
        floatx4 ld = *(const floatx4*)(W + (size_t)(k0 + r) * 64 + c * 4);
#pragma unroll
        for (int j = 0; j < 4; j++) Tt[r][c * 4 + j] = ld[j];
    }
    __syncthreads();
#pragma unroll
    for (int i = 0; i < 2; i++) {
        int v = i * 256 + tid, n = v >> 3, k8 = v & 7;
        bf16x8 w;
#pragma unroll
        for (int j = 0; j < 8; j++) w[j] = (short)f2bf(Tt[k8 * 8 + j][n]);
        *(bf16x8*)&WT[(size_t)(mat * 64 + n) * 1024 + k0 + k8 * 8] = w;
    }
}

// ---------------- projection: q,k,v = x @ W{q,k,v} ----------------
// grid 256, block 512 (8 waves = 4 row-strips x 2 col-groups). BM=64.
// Double-buffered reg-prefetch, one barrier per chunk.
// vb (stored [b][d][s]) now goes through a padded LDS transpose tile and is
// stored fully coalesced (old path: 2B scalar scatter at 8KB lane stride,
// ~8x write amplification + 1M-store issue tail).
#define QSCALE 0.18033688011112042f
__launch_bounds__(512, 2)
__global__ void proj_qkv(const float* __restrict__ X, const unsigned short* __restrict__ WT,
                         unsigned short* __restrict__ qb, unsigned short* __restrict__ kb,
                         unsigned short* __restrict__ vb) {
    __shared__ __align__(16) float          X0[64 * 64], X1[64 * 64];     // 16 KB each
    __shared__ __align__(16) unsigned short W0[192 * 64], W1[192 * 64];   // 24 KB each
    __shared__ __align__(16) unsigned short Vt[64][72];                   // 9 KB V^T bounce
    const int tid = threadIdx.x;
    const int wave = tid >> 6, lane = tid & 63;
    const int quad = lane >> 4, l16 = lane & 15;
    const int strip = wave >> 1;            // rows strip*16..+16
    const int cg = wave & 1;                // cols cg*96..+96
    const int row0 = blockIdx.x * 64;
    const int m = strip * 16 + l16;

    floatx4 acc[6];
#pragma unroll
    for (int i = 0; i < 6; i++) acc[i] = (floatx4){0.f, 0.f, 0.f, 0.f};

    int xu[2], xr[2], xc[2], wu[3], wr[3], wc[3];
#pragma unroll
    for (int i = 0; i < 2; i++) {
        xu[i] = i * 512 + tid; xr[i] = xu[i] >> 4; xc[i] = (xu[i] & 15) ^ (xr[i] & 15);
    }
#pragma unroll
    for (int i = 0; i < 3; i++) {
        wu[i] = i * 512 + tid; wr[i] = wu[i] >> 3; wc[i] = (wu[i] & 7) ^ (wr[i] & 7);
    }
    floatx4 xpre[2], wpre[3];
    auto issue = [&](int k0) {
#pragma unroll
        for (int i = 0; i < 2; i++)
            xpre[i] = *(const floatx4*)(X + (size_t)(row0 + xr[i]) * DIN + k0 + xc[i] * 4);
#pragma unroll
        for (int i = 0; i < 3; i++)
            wpre[i] = *(const floatx4*)(WT + (size_t)wr[i] * 1024 + k0 + wc[i] * 8);
    };

    issue(0);
    for (int kc = 0; kc < 16; kc++) {
        float*          Xd = (kc & 1) ? X1 : X0;
        unsigned short* Wd = (kc & 1) ? W1 : W0;
#pragma unroll
        for (int i = 0; i < 2; i++) *(floatx4*)&Xd[xu[i] * 4] = xpre[i];
#pragma unroll
        for (int i = 0; i < 3; i++) *(floatx4*)&Wd[wu[i] * 8] = wpre[i];
        if (kc < 15) issue((kc + 1) * 64);   // in flight across the barrier
        __syncthreads();

        bf16x8 af[2];
#pragma unroll
        for (int ks = 0; ks < 2; ks++) {
            floatx4 x0 = *(const floatx4*)&Xd[m * 64 + ((ks * 8 + quad * 2 + 0) ^ (m & 15)) * 4];
            floatx4 x1 = *(const floatx4*)&Xd[m * 64 + ((ks * 8 + quad * 2 + 1) ^ (m & 15)) * 4];
#pragma unroll
            for (int j = 0; j < 4; j++) {
                af[ks][j]     = (short)f2bf(x0[j]);
                af[ks][j + 4] = (short)f2bf(x1[j]);
            }
        }
#pragma unroll
        for (int i = 0; i < 6; i++) {
            const int nrow = (cg * 6 + i) * 16 + l16;
#pragma unroll
            for (int ks = 0; ks < 2; ks++) {
                const int c = ks * 4 + quad;
                bf16x8 bfrag = *(const bf16x8*)&Wd[nrow * 64 + (c ^ (nrow & 7)) * 8];
                acc[i] = __builtin_amdgcn_mfma_f32_16x16x32_bf16(af[ks], bfrag, acc[i], 0, 0, 0);
            }
        }
    }
#pragma unroll
    for (int i = 0; i < 6; i++) {
        const int nt = cg * 6 + i;
        const int mat = nt >> 2;
        const int col = (nt & 3) * 16 + l16;
#pragma unroll
        for (int r = 0; r < 4; r++) {
            const int orow = row0 + strip * 16 + quad * 4 + r;
            float v = acc[i][r];
            if (mat == 0) {
                qb[(size_t)orow * 64 + col] = f2bf(v * QSCALE);
            } else if (mat == 1) {
                kb[(size_t)orow * 64 + col] = f2bf(v);
            } else {  // V^T via LDS: Vt[d][sq_local], bank-stride 4 -> 2-way (free)
                Vt[col][strip * 16 + quad * 4 + r] = f2bf(v);
            }
        }
    }
    __syncthreads();
    {   // cooperative coalesced store of V^T tile: 64 d-rows x 128 B
        const int b = row0 >> 12, sq0 = row0 & 4095;
        const int r = tid >> 3, seg = tid & 7;
        bf16x8 w = *(const bf16x8*)&Vt[r][seg * 8];
        *(bf16x8*)&vb[((size_t)(b * 64 + r)) * SEQ + sq0 + seg * 8] = w;
    }
}

// ---------------- flash attention, causal, fixed-base softmax ----------------
// Q-tile 128 (4 waves x 32 q-rows = 2 strips each); K/V double-buffered,
// ONE barrier per 64-key tile; split-K 4 -> grid 32 qt x 4 batch x 4 = 512
// blocks, 50 KB LDS -> 2 blocks/CU resident. O-tile bounced through the
// wave-private P strip for fully-coalesced opart stores. Empty splits write
// zeros so merge is unconditional.
__launch_bounds__(256, 3)
__global__ void attn(const unsigned short* __restrict__ qb, const unsigned short* __restrict__ kb,
                     const unsigned short* __restrict__ vb, unsigned short* __restrict__ opart,
                     float* __restrict__ lpart) {
    __shared__ __align__(16) unsigned short K0[64 * 64], K1[64 * 64];   // 8 KB each [key][d] swz
    __shared__ __align__(16) unsigned short V0[64 * 64], V1[64 * 64];   // 8 KB each [d][key] swz
    __shared__ __align__(16) unsigned short Pl[4][32 * 72];             // 18 KB [q32][key64+pad]

    const int bid = blockIdx.x;
    const int qt = 31 - (bid >> 4);          // heavy (large qt) dispatched first
    const int batch = (bid >> 2) & 3;
    const int s = bid & 3;
    const int q0 = qt * 128;
    const int T = 2 * qt + 2;                // 64-key tiles in causal range
    const int lo = (T * s) >> 2, hi = (T * (s + 1)) >> 2;

    const int tid = threadIdx.x;
    const int wave = tid >> 6, lane = tid & 63;
    const int quad = lane >> 4, l16 = lane & 15;

    const unsigned short* qr = qb + (size_t)(batch * SEQ + q0 + wave * 32 + l16) * 64;
    bf16x8 qa[2][2];                         // [strip][ks]
    qa[0][0] = *(const bf16x8*)(qr + quad * 8);
    qa[0][1] = *(const bf16x8*)(qr + 32 + quad * 8);
    qa[1][0] = *(const bf16x8*)(qr + 16 * 64 + quad * 8);
    qa[1][1] = *(const bf16x8*)(qr + 16 * 64 + 32 + quad * 8);

    floatx4 o[2][4];                         // o[st][nt][r] = O[q=l16 of strip][d=nt*16+quad*4+r]
#pragma unroll
    for (int st = 0; st < 2; st++)
#pragma unroll
        for (int i = 0; i < 4; i++) o[st][i] = (floatx4){0.f, 0.f, 0.f, 0.f};
    float ls[2] = {0.f, 0.f};

    const unsigned short* kbase = kb + (size_t)batch * SEQ * 64;
    const unsigned short* vbase = vb + (size_t)batch * 64 * SEQ;
    unsigned short* P = &Pl[wave][0];

    // staging: K 512 16B-units + V 512 units, 2+2 per thread
    int ku[2], kr[2], kc_[2], vu[2], vd[2], vc[2];
#pragma unroll
    for (int i = 0; i < 2; i++) {
        ku[i] = i * 256 + tid; kr[i] = ku[i] >> 3; kc_[i] = (ku[i] & 7) ^ (kr[i] & 7);
        vu[i] = i * 256 + tid; vd[i] = vu[i] >> 3; vc[i] = (vu[i] & 7) ^ (vd[i] & 7);
    }
    floatx4 kpre[2], vpre[2];
    auto issue = [&](int k0) {
#pragma unroll
        for (int i = 0; i < 2; i++)
            kpre[i] = *(const floatx4*)(kbase + (size_t)(k0 + kr[i]) * 64 + kc_[i] * 8);
#pragma unroll
        for (int i = 0; i < 2; i++)
            vpre[i] = *(const floatx4*)(vbase + (size_t)vd[i] * SEQ + k0 + vc[i] * 8);
    };

    if (lo < hi) issue(lo * 64);
    for (int kt = lo; kt < hi; kt++) {
        unsigned short* Kd = (kt & 1) ? K1 : K0;
        unsigned short* Vd = (kt & 1) ? V1 : V0;
#pragma unroll
        for (int i = 0; i < 2; i++) *(floatx4*)&Kd[ku[i] * 8] = kpre[i];
#pragma unroll
        for (int i = 0; i < 2; i++) *(floatx4*)&Vd[vu[i] * 8] = vpre[i];
        if (kt + 1 < hi) issue((kt + 1) * 64);   // lands during compute below
        __syncthreads();                     // publishes tile kt

        const int k0 = kt * 64;
        // S^T: sc[st][nt][r] = S[q=l16 of strip][key=k0+nt*16+quad*4+r]
        floatx4 sc[2][4];
#pragma unroll
        for (int st = 0; st < 2; st++)
#pragma unroll
            for (int nt = 0; nt < 4; nt++) sc[st][nt] = (floatx4){0.f, 0.f, 0.f, 0.f};
#pragma unroll
        for (int ks = 0; ks < 2; ks++) {
#pragma unroll
            for (int nt = 0; nt < 4; nt++) {
                const int key = nt * 16 + l16;
                bf16x8 ak = *(const bf16x8*)&Kd[key * 64 + (((ks * 4 + quad)) ^ (key & 7)) * 8];
                sc[0][nt] = __builtin_amdgcn_mfma_f32_16x16x32_bf16(ak, qa[0][ks], sc[0][nt], 0, 0, 0);
                sc[1][nt] = __builtin_amdgcn_mfma_f32_16x16x32_bf16(ak, qa[1][ks], sc[1][nt], 0, 0, 0);
            }
        }
        if (kt >= T - 2) {                   // diagonal region: causal mask
#pragma unroll
            for (int st = 0; st < 2; st++) {
                const int qg = q0 + wave * 32 + st * 16 + l16;
#pragma unroll
                for (int nt = 0; nt < 4; nt++)
#pragma unroll
                    for (int r = 0; r < 4; r++) {
                        const int kg = k0 + nt * 16 + quad * 4 + r;
                        if (kg > qg) sc[st][nt][r] = -1e30f;
                    }
            }
        }
#pragma unroll
        for (int st = 0; st < 2; st++) {
#pragma unroll
            for (int nt = 0; nt < 4; nt++) {
                // p = exp2(s) (fixed-base softmax, log2 domain, q pre-scaled)
                float v0 = EXP2(sc[st][nt][0]), v1 = EXP2(sc[st][nt][1]);
                float v2 = EXP2(sc[st][nt][2]), v3 = EXP2(sc[st][nt][3]);
                // truncate to bf16; lsum accumulates the SAME truncated values
                unsigned int u0 = fasu(v0) & 0xffff0000u, u1 = fasu(v1) & 0xffff0000u;
                unsigned int u2 = fasu(v2) & 0xffff0000u, u3 = fasu(v3) & 0xffff0000u;
                ls[st] += (uasf(u0) + uasf(u1)) + (uasf(u2) + uasf(u3));
                uint2 w;
                w.x = (u0 >> 16) | u1;       // keys quad*4+0, +1
                w.y = (u2 >> 16) | u3;       // keys quad*4+2, +3
                *(uint2*)&P[(st * 16 + l16) * 72 + nt * 16 + quad * 4] = w;
            }
        }
        // PV: O^T = A=V^T (vb is [d][s]) x B=P^T; V frag shared by both strips
#pragma unroll
        for (int ks = 0; ks < 2; ks++) {
            bf16x8 pb0 = *(const bf16x8*)&P[(0  + l16) * 72 + ks * 32 + quad * 8];
            bf16x8 pb1 = *(const bf16x8*)&P[(16 + l16) * 72 + ks * 32 + quad * 8];
#pragma unroll
            for (int nt = 0; nt < 4; nt++) {
                const int d = nt * 16 + l16;
                bf16x8 av = *(const bf16x8*)&Vd[d * 64 + (((ks * 4 + quad)) ^ (d & 7)) * 8];
                o[0][nt] = __builtin_amdgcn_mfma_f32_16x16x32_bf16(av, pb0, o[0][nt], 0, 0, 0);
                o[1][nt] = __builtin_amdgcn_mfma_f32_16x16x32_bf16(av, pb1, o[1][nt], 0, 0, 0);
            }
        }
    }

    // epilogue: un-normalized bf16 partial + row sums (zeros if empty split).
    // O-tile bounced through the wave-private P strip -> coalesced 16B stores.
    unsigned short* ob = opart + (size_t)s * (4 * SEQ * 64)
                       + (size_t)(batch * SEQ + q0 + wave * 32) * 64;
    float* lb = lpart + (size_t)s * (4 * SEQ) + (batch * SEQ + q0 + wave * 32);
#pragma unroll
    for (int st = 0; st < 2; st++) {
        float l = ls[st];
        l += __shfl_xor(l, 16);
        l += __shfl_xor(l, 32);
        if (quad == 0) lb[st * 16 + l16] = l;
#pragma unroll
        for (int nt = 0; nt < 4; nt++) {
            ushortx4 w;
#pragma unroll
            for (int r = 0; r < 4; r++) w[r] = f2bf(o[st][nt][r]);
            *(ushortx4*)&P[(st * 16 + l16) * 72 + nt * 16 + quad * 4] = w;
        }
    }
#pragma unroll
    for (int j = 0; j < 4; j++) {            // 32 rows x 128 B, 8 lanes/row
        const int row = j * 8 + (lane >> 3), seg = lane & 7;
        bf16x8 w = *(const bf16x8*)&P[row * 72 + seg * 8];
        *(bf16x8*)&ob[row * 64 + seg * 8] = w;
    }
}

// ---------------- merge the four split-K partials ----------------
__global__ void merge(const unsigned short* __restrict__ opart, const float* __restrict__ lpart,
                      float* __restrict__ out) {
    int idx = blockIdx.x * 256 + threadIdx.x;   // [0, 262144): 4-col units
    int row = idx >> 4, c4 = idx & 15;
    float l = lpart[row] + lpart[4 * SEQ + row] + lpart[8 * SEQ + row] + lpart[12 * SEQ + row];
    float inv = 1.f / l;
    floatx4 acc = (floatx4){0.f, 0.f, 0.f, 0.f};
#pragma unroll
    for (int s = 0; s < 4; s++) {
        ushortx4 u = *(const ushortx4*)(opart + (size_t)s * (4 * SEQ * 64)
                                        + (size_t)row * 64 + c4 * 4);
#pragma unroll
        for (int j = 0; j < 4; j++) acc[j] += bf2f(u[j]);
    }
    acc *= inv;
    *(floatx4*)(out + (size_t)row * 64 + c4 * 4) = acc;
}

extern "C" void kernel_launch(void* const* d_in, const int* in_sizes, int n_in,
                              void* d_out, int out_size, void* d_ws, size_t ws_size,
                              hipStream_t stream) {
    const float* X  = (const float*)d_in[0];
    const float* Wq = (const float*)d_in[1];
    const float* Wk = (const float*)d_in[2];
    const float* Wv = (const float*)d_in[3];
    float* out = (float*)d_out;
    char* ws = (char*)d_ws;
    unsigned short* WT    = (unsigned short*)(ws + 0);         // 384 KB
    unsigned short* qb    = (unsigned short*)(ws + 393216);    // 2 MB
    unsigned short* kb    = (unsigned short*)(ws + 2490368);   // 2 MB
    unsigned short* vb    = (unsigned short*)(ws + 4587520);   // 2 MB
    unsigned short* opart = (unsigned short*)(ws + 6684672);   // 8 MB (4 slots, bf16)
    float*          lpart = (float*)(ws + 15073280);           // 256 KB

    hipLaunchKernelGGL(wt_prep,  dim3(48),   dim3(256), 0, stream, Wq, Wk, Wv, WT);
    hipLaunchKernelGGL(proj_qkv, dim3(256),  dim3(512), 0, stream, X, WT, qb, kb, vb);
    hipLaunchKernelGGL(attn,     dim3(512),  dim3(256), 0, stream, qb, kb, vb, opart, lpart);
    hipLaunchKernelGGL(merge,    dim3(1024), dim3(256), 0, stream, opart, lpart, out);
}

// Round 4
// 132.060 us; speedup vs baseline: 1.0263x; 1.0067x over previous
//
#include <hip/hip_runtime.h>
#include <stdint.h>

#define SEQ   4096
#define DIN   1024

typedef __attribute__((ext_vector_type(8))) short bf16x8;
typedef __attribute__((ext_vector_type(4))) float floatx4;
typedef __attribute__((ext_vector_type(4))) unsigned short ushortx4;

#if __has_builtin(__builtin_amdgcn_exp2f)
#define EXP2(x) __builtin_amdgcn_exp2f(x)
#else
#define EXP2(x) exp2f(x)
#endif

__device__ __forceinline__ unsigned short f2bf(float f) {
    union { float f; unsigned int u; } v; v.f = f;
    unsigned int u = v.u + 0x7fffu + ((v.u >> 16) & 1u);
    return (unsigned short)(u >> 16);
}
__device__ __forceinline__ float bf2f(unsigned short h) {
    union { unsigned int u; float f; } v; v.u = ((unsigned int)h) << 16;
    return v.f;
}
__device__ __forceinline__ float uasf(unsigned int u) {
    union { unsigned int u; float f; } v; v.u = u; return v.f;
}
__device__ __forceinline__ unsigned int fasu(float f) {
    union { float f; unsigned int u; } v; v.f = f; return v.u;
}

// ---------------- prep: WT[mat*64+n][k] = bf16(W[k][n]) ----------------
// Coalesced both sides via 64x64 LDS transpose tile. 48 blocks = 3 mats x 16 k-tiles.
__global__ void wt_prep(const float* __restrict__ Wq, const float* __restrict__ Wk,
                        const float* __restrict__ Wv, unsigned short* __restrict__ WT) {
    __shared__ float Tt[64][65];
    const int tid = threadIdx.x;
    const int mat = blockIdx.x >> 4, kt = blockIdx.x & 15, k0 = kt * 64;
    const float* W = (mat == 0) ? Wq : ((mat == 1) ? Wk : Wv);
#pragma unroll
    for (int i = 0; i < 4; i++) {
        int u = i * 256 + tid, r = u >> 4, c = u & 15;
        floatx4 ld = *(const floatx4*)(W + (size_t)(k0 + r) * 64 + c * 4);
#pragma unroll
        for (int j = 0; j < 4; j++) Tt[r][c * 4 + j] = ld[j];
    }
    __syncthreads();
#pragma unroll
    for (int i = 0; i < 2; i++) {
        int v = i * 256 + tid, n = v >> 3, k8 = v & 7;
        bf16x8 w;
#pragma unroll
        for (int j = 0; j < 8; j++) w[j] = (short)f2bf(Tt[k8 * 8 + j][n]);
        *(bf16x8*)&WT[(size_t)(mat * 64 + n) * 1024 + k0 + k8 * 8] = w;
    }
}

// ---------------- projection: q,k,v = x @ W{q,k,v} ----------------
// grid 256, block 512 (8 waves = 4 row-strips x 2 col-groups). BM=64.
// X staged to LDS as bf16 (converted ONCE at stage time, not per-wave at
// read time): X buffers 16->8 KB, LDS total 89->73 KB => 2 blocks/CU
// (launch_bounds(512,4): 4 waves/EU = 2 blocks, VGPR cap 128). The
// co-resident block overlaps the per-chunk barrier drain (m114 mechanism).
// vb goes through a padded LDS transpose tile, stored fully coalesced.
#define QSCALE 0.18033688011112042f
__launch_bounds__(512, 4)
__global__ void proj_qkv(const float* __restrict__ X, const unsigned short* __restrict__ WT,
                         unsigned short* __restrict__ qb, unsigned short* __restrict__ kb,
                         unsigned short* __restrict__ vb) {
    __shared__ __align__(16) unsigned short X0[64 * 64], X1[64 * 64];     //  8 KB each, bf16
    __shared__ __align__(16) unsigned short W0[192 * 64], W1[192 * 64];   // 24 KB each
    __shared__ __align__(16) unsigned short Vt[64][72];                   //  9 KB V^T bounce
    const int tid = threadIdx.x;
    const int wave = tid >> 6, lane = tid & 63;
    const int quad = lane >> 4, l16 = lane & 15;
    const int strip = wave >> 1;            // rows strip*16..+16
    const int cg = wave & 1;                // cols cg*96..+96
    const int row0 = blockIdx.x * 64;
    const int m = strip * 16 + l16;

    floatx4 acc[6];
#pragma unroll
    for (int i = 0; i < 6; i++) acc[i] = (floatx4){0.f, 0.f, 0.f, 0.f};

    // X staging: one 16B bf16 unit per thread (8 floats in, 8 bf16 out).
    const int xrow = tid >> 3, xuc = tid & 7;
    const int xdst = (xrow * 8 + (xuc ^ (xrow & 7))) * 8;   // swizzled ushort index
    int wu[3], wr[3], wc[3];
#pragma unroll
    for (int i = 0; i < 3; i++) {
        wu[i] = i * 512 + tid; wr[i] = wu[i] >> 3; wc[i] = (wu[i] & 7) ^ (wr[i] & 7);
    }
    floatx4 xpre[2], wpre[3];
    auto issue = [&](int k0) {
#pragma unroll
        for (int i = 0; i < 2; i++)
            xpre[i] = *(const floatx4*)(X + (size_t)(row0 + xrow) * DIN + k0 + xuc * 8 + i * 4);
#pragma unroll
        for (int i = 0; i < 3; i++)
            wpre[i] = *(const floatx4*)(WT + (size_t)wr[i] * 1024 + k0 + wc[i] * 8);
    };

    issue(0);
    for (int kc = 0; kc < 16; kc++) {
        unsigned short* Xd = (kc & 1) ? X1 : X0;
        unsigned short* Wd = (kc & 1) ? W1 : W0;
        {   // convert-at-stage: 8 f2bf per thread per chunk (was 16/lane at read)
            bf16x8 xw;
#pragma unroll
            for (int j = 0; j < 4; j++) { xw[j] = (short)f2bf(xpre[0][j]); xw[j + 4] = (short)f2bf(xpre[1][j]); }
            *(bf16x8*)&Xd[xdst] = xw;
        }
#pragma unroll
        for (int i = 0; i < 3; i++) *(floatx4*)&Wd[wu[i] * 8] = wpre[i];
        if (kc < 15) issue((kc + 1) * 64);   // in flight across the barrier
        __syncthreads();

        bf16x8 af[2];
#pragma unroll
        for (int ks = 0; ks < 2; ks++)       // single swizzled b128, no VALU
            af[ks] = *(const bf16x8*)&Xd[m * 64 + (((ks * 4 + quad) ^ (m & 7)) * 8)];
#pragma unroll
        for (int i = 0; i < 6; i++) {
            const int nrow = (cg * 6 + i) * 16 + l16;
#pragma unroll
            for (int ks = 0; ks < 2; ks++) {
                const int c = ks * 4 + quad;
                bf16x8 bfrag = *(const bf16x8*)&Wd[nrow * 64 + (c ^ (nrow & 7)) * 8];
                acc[i] = __builtin_amdgcn_mfma_f32_16x16x32_bf16(af[ks], bfrag, acc[i], 0, 0, 0);
            }
        }
    }
#pragma unroll
    for (int i = 0; i < 6; i++) {
        const int nt = cg * 6 + i;
        const int mat = nt >> 2;
        const int col = (nt & 3) * 16 + l16;
#pragma unroll
        for (int r = 0; r < 4; r++) {
            const int orow = row0 + strip * 16 + quad * 4 + r;
            float v = acc[i][r];
            if (mat == 0) {
                qb[(size_t)orow * 64 + col] = f2bf(v * QSCALE);
            } else if (mat == 1) {
                kb[(size_t)orow * 64 + col] = f2bf(v);
            } else {  // V^T via LDS: Vt[d][sq_local], bank-stride 4 -> 2-way (free)
                Vt[col][strip * 16 + quad * 4 + r] = f2bf(v);
            }
        }
    }
    __syncthreads();
    {   // cooperative coalesced store of V^T tile: 64 d-rows x 128 B
        const int b = row0 >> 12, sq0 = row0 & 4095;
        const int r = tid >> 3, seg = tid & 7;
        bf16x8 w = *(const bf16x8*)&Vt[r][seg * 8];
        *(bf16x8*)&vb[((size_t)(b * 64 + r)) * SEQ + sq0 + seg * 8] = w;
    }
}

// ---------------- flash attention, causal, fixed-base softmax ----------------
// Q-tile 128 (4 waves x 32 q-rows = 2 strips each); K/V double-buffered,
// ONE barrier per 64-key tile; split-K 4 -> grid 32 qt x 4 batch x 4 = 512
// blocks, 50 KB LDS -> 3 blocks/CU resident. O-tile bounced through the
// wave-private P strip for fully-coalesced opart stores. Empty splits write
// zeros so merge is unconditional.
__launch_bounds__(256, 3)
__global__ void attn(const unsigned short* __restrict__ qb, const unsigned short* __restrict__ kb,
                     const unsigned short* __restrict__ vb, unsigned short* __restrict__ opart,
                     float* __restrict__ lpart) {
    __shared__ __align__(16) unsigned short K0[64 * 64], K1[64 * 64];   // 8 KB each [key][d] swz
    __shared__ __align__(16) unsigned short V0[64 * 64], V1[64 * 64];   // 8 KB each [d][key] swz
    __shared__ __align__(16) unsigned short Pl[4][32 * 72];             // 18 KB [q32][key64+pad]

    const int bid = blockIdx.x;
    const int qt = 31 - (bid >> 4);          // heavy (large qt) dispatched first
    const int batch = (bid >> 2) & 3;
    const int s = bid & 3;
    const int q0 = qt * 128;
    const int T = 2 * qt + 2;                // 64-key tiles in causal range
    const int lo = (T * s) >> 2, hi = (T * (s + 1)) >> 2;

    const int tid = threadIdx.x;
    const int wave = tid >> 6, lane = tid & 63;
    const int quad = lane >> 4, l16 = lane & 15;

    const unsigned short* qr = qb + (size_t)(batch * SEQ + q0 + wave * 32 + l16) * 64;
    bf16x8 qa[2][2];                         // [strip][ks]
    qa[0][0] = *(const bf16x8*)(qr + quad * 8);
    qa[0][1] = *(const bf16x8*)(qr + 32 + quad * 8);
    qa[1][0] = *(const bf16x8*)(qr + 16 * 64 + quad * 8);
    qa[1][1] = *(const bf16x8*)(qr + 16 * 64 + 32 + quad * 8);

    floatx4 o[2][4];                         // o[st][nt][r] = O[q=l16 of strip][d=nt*16+quad*4+r]
#pragma unroll
    for (int st = 0; st < 2; st++)
#pragma unroll
        for (int i = 0; i < 4; i++) o[st][i] = (floatx4){0.f, 0.f, 0.f, 0.f};
    float ls[2] = {0.f, 0.f};

    const unsigned short* kbase = kb + (size_t)batch * SEQ * 64;
    const unsigned short* vbase = vb + (size_t)batch * 64 * SEQ;
    unsigned short* P = &Pl[wave][0];

    // staging: K 512 16B-units + V 512 units, 2+2 per thread
    int ku[2], kr[2], kc_[2], vu[2], vd[2], vc[2];
#pragma unroll
    for (int i = 0; i < 2; i++) {
        ku[i] = i * 256 + tid; kr[i] = ku[i] >> 3; kc_[i] = (ku[i] & 7) ^ (kr[i] & 7);
        vu[i] = i * 256 + tid; vd[i] = vu[i] >> 3; vc[i] = (vu[i] & 7) ^ (vd[i] & 7);
    }
    floatx4 kpre[2], vpre[2];
    auto issue = [&](int k0) {
#pragma unroll
        for (int i = 0; i < 2; i++)
            kpre[i] = *(const floatx4*)(kbase + (size_t)(k0 + kr[i]) * 64 + kc_[i] * 8);
#pragma unroll
        for (int i = 0; i < 2; i++)
            vpre[i] = *(const floatx4*)(vbase + (size_t)vd[i] * SEQ + k0 + vc[i] * 8);
    };

    if (lo < hi) issue(lo * 64);
    for (int kt = lo; kt < hi; kt++) {
        unsigned short* Kd = (kt & 1) ? K1 : K0;
        unsigned short* Vd = (kt & 1) ? V1 : V0;
#pragma unroll
        for (int i = 0; i < 2; i++) *(floatx4*)&Kd[ku[i] * 8] = kpre[i];
#pragma unroll
        for (int i = 0; i < 2; i++) *(floatx4*)&Vd[vu[i] * 8] = vpre[i];
        if (kt + 1 < hi) issue((kt + 1) * 64);   // lands during compute below
        __syncthreads();                     // publishes tile kt

        const int k0 = kt * 64;
        // S^T: sc[st][nt][r] = S[q=l16 of strip][key=k0+nt*16+quad*4+r]
        floatx4 sc[2][4];
#pragma unroll
        for (int st = 0; st < 2; st++)
#pragma unroll
            for (int nt = 0; nt < 4; nt++) sc[st][nt] = (floatx4){0.f, 0.f, 0.f, 0.f};
#pragma unroll
        for (int ks = 0; ks < 2; ks++) {
#pragma unroll
            for (int nt = 0; nt < 4; nt++) {
                const int key = nt * 16 + l16;
                bf16x8 ak = *(const bf16x8*)&Kd[key * 64 + (((ks * 4 + quad)) ^ (key & 7)) * 8];
                sc[0][nt] = __builtin_amdgcn_mfma_f32_16x16x32_bf16(ak, qa[0][ks], sc[0][nt], 0, 0, 0);
                sc[1][nt] = __builtin_amdgcn_mfma_f32_16x16x32_bf16(ak, qa[1][ks], sc[1][nt], 0, 0, 0);
            }
        }
        if (kt >= T - 2) {                   // diagonal region: causal mask
#pragma unroll
            for (int st = 0; st < 2; st++) {
                const int qg = q0 + wave * 32 + st * 16 + l16;
#pragma unroll
                for (int nt = 0; nt < 4; nt++)
#pragma unroll
                    for (int r = 0; r < 4; r++) {
                        const int kg = k0 + nt * 16 + quad * 4 + r;
                        if (kg > qg) sc[st][nt][r] = -1e30f;
                    }
            }
        }
#pragma unroll
        for (int st = 0; st < 2; st++) {
#pragma unroll
            for (int nt = 0; nt < 4; nt++) {
                // p = exp2(s) (fixed-base softmax, log2 domain, q pre-scaled)
                float v0 = EXP2(sc[st][nt][0]), v1 = EXP2(sc[st][nt][1]);
                float v2 = EXP2(sc[st][nt][2]), v3 = EXP2(sc[st][nt][3]);
                // truncate to bf16; lsum accumulates the SAME truncated values
                unsigned int u0 = fasu(v0) & 0xffff0000u, u1 = fasu(v1) & 0xffff0000u;
                unsigned int u2 = fasu(v2) & 0xffff0000u, u3 = fasu(v3) & 0xffff0000u;
                ls[st] += (uasf(u0) + uasf(u1)) + (uasf(u2) + uasf(u3));
                uint2 w;
                w.x = (u0 >> 16) | u1;       // keys quad*4+0, +1
                w.y = (u2 >> 16) | u3;       // keys quad*4+2, +3
                *(uint2*)&P[(st * 16 + l16) * 72 + nt * 16 + quad * 4] = w;
            }
        }
        // PV: O^T = A=V^T (vb is [d][s]) x B=P^T; V frag shared by both strips
#pragma unroll
        for (int ks = 0; ks < 2; ks++) {
            bf16x8 pb0 = *(const bf16x8*)&P[(0  + l16) * 72 + ks * 32 + quad * 8];
            bf16x8 pb1 = *(const bf16x8*)&P[(16 + l16) * 72 + ks * 32 + quad * 8];
#pragma unroll
            for (int nt = 0; nt < 4; nt++) {
                const int d = nt * 16 + l16;
                bf16x8 av = *(const bf16x8*)&Vd[d * 64 + (((ks * 4 + quad)) ^ (d & 7)) * 8];
                o[0][nt] = __builtin_amdgcn_mfma_f32_16x16x32_bf16(av, pb0, o[0][nt], 0, 0, 0);
                o[1][nt] = __builtin_amdgcn_mfma_f32_16x16x32_bf16(av, pb1, o[1][nt], 0, 0, 0);
            }
        }
    }

    // epilogue: un-normalized bf16 partial + row sums (zeros if empty split).
    // O-tile bounced through the wave-private P strip -> coalesced 16B stores.
    unsigned short* ob = opart + (size_t)s * (4 * SEQ * 64)
                       + (size_t)(batch * SEQ + q0 + wave * 32) * 64;
    float* lb = lpart + (size_t)s * (4 * SEQ) + (batch * SEQ + q0 + wave * 32);
#pragma unroll
    for (int st = 0; st < 2; st++) {
        float l = ls[st];
        l += __shfl_xor(l, 16);
        l += __shfl_xor(l, 32);
        if (quad == 0) lb[st * 16 + l16] = l;
#pragma unroll
        for (int nt = 0; nt < 4; nt++) {
            ushortx4 w;
#pragma unroll
            for (int r = 0; r < 4; r++) w[r] = f2bf(o[st][nt][r]);
            *(ushortx4*)&P[(st * 16 + l16) * 72 + nt * 16 + quad * 4] = w;
        }
    }
#pragma unroll
    for (int j = 0; j < 4; j++) {            // 32 rows x 128 B, 8 lanes/row
        const int row = j * 8 + (lane >> 3), seg = lane & 7;
        bf16x8 w = *(const bf16x8*)&P[row * 72 + seg * 8];
        *(bf16x8*)&ob[row * 64 + seg * 8] = w;
    }
}

// ---------------- merge the four split-K partials ----------------
__global__ void merge(const unsigned short* __restrict__ opart, const float* __restrict__ lpart,
                      float* __restrict__ out) {
    int idx = blockIdx.x * 256 + threadIdx.x;   // [0, 262144): 4-col units
    int row = idx >> 4, c4 = idx & 15;
    float l = lpart[row] + lpart[4 * SEQ + row] + lpart[8 * SEQ + row] + lpart[12 * SEQ + row];
    float inv = 1.f / l;
    floatx4 acc = (floatx4){0.f, 0.f, 0.f, 0.f};
#pragma unroll
    for (int s = 0; s < 4; s++) {
        ushortx4 u = *(const ushortx4*)(opart + (size_t)s * (4 * SEQ * 64)
                                        + (size_t)row * 64 + c4 * 4);
#pragma unroll
        for (int j = 0; j < 4; j++) acc[j] += bf2f(u[j]);
    }
    acc *= inv;
    *(floatx4*)(out + (size_t)row * 64 + c4 * 4) = acc;
}

extern "C" void kernel_launch(void* const* d_in, const int* in_sizes, int n_in,
                              void* d_out, int out_size, void* d_ws, size_t ws_size,
                              hipStream_t stream) {
    const float* X  = (const float*)d_in[0];
    const float* Wq = (const float*)d_in[1];
    const float* Wk = (const float*)d_in[2];
    const float* Wv = (const float*)d_in[3];
    float* out = (float*)d_out;
    char* ws = (char*)d_ws;
    unsigned short* WT    = (unsigned short*)(ws + 0);         // 384 KB
    unsigned short* qb    = (unsigned short*)(ws + 393216);    // 2 MB
    unsigned short* kb    = (unsigned short*)(ws + 2490368);   // 2 MB
    unsigned short* vb    = (unsigned short*)(ws + 4587520);   // 2 MB
    unsigned short* opart = (unsigned short*)(ws + 6684672);   // 8 MB (4 slots, bf16)
    float*          lpart = (float*)(ws + 15073280);           // 256 KB

    hipLaunchKernelGGL(wt_prep,  dim3(48),   dim3(256), 0, stream, Wq, Wk, Wv, WT);
    hipLaunchKernelGGL(proj_qkv, dim3(256),  dim3(512), 0, stream, X, WT, qb, kb, vb);
    hipLaunchKernelGGL(attn,     dim3(512),  dim3(256), 0, stream, qb, kb, vb, opart, lpart);
    hipLaunchKernelGGL(merge,    dim3(1024), dim3(256), 0, stream, opart, lpart, out);
}